// Round 5
// baseline (1034.061 us; speedup 1.0000x reference)
//
#include <hip/hip_runtime.h>

// ---- problem constants ----
constexpr int NY = 384, NX = 384, S = 4, NREC = 96, NT = 600;
constexpr int K = 8;                    // timesteps per launch
constexpr int T = 48;                   // interior tile side
constexpr int L = 80;                   // extended tile side = T + 4K
constexpr int PAD = 16;                 // = 2K global guard
constexpr int PX = NX + 2 * PAD;        // 416
constexpr int PNN = PX * PX;            // 173056
constexpr int TB = NX / T;              // 8 tiles per dim
constexpr int SP = 84;                  // LDS row stride (floats), padded
constexpr int NPAIR = (L / 2) * (L / 4);// 800 vertical quad-pairs
constexpr int TPB = 1024;               // one pair per thread, 16 waves/CU
constexpr float D0 = 323.80102870228766f;
constexpr float HALF_DT = 0.00025f;     // 0.5*DT
constexpr float DT2 = 2.5e-7f;          // DT*DT
constexpr float C0 = -1.0f / 12.0f, C1 = 4.0f / 3.0f, C2 = -2.5f;
constexpr float INV_DX2 = 0.0625f;      // 1/DX^2 exact

__device__ __forceinline__ float sigma_of(int y, int x) {
    float yf = (float)y, xf = (float)x;
    float a = fmaxf((20.0f - yf) / 20.0f, 0.0f);
    float b = fmaxf((yf - 363.0f) / 20.0f, 0.0f);
    float m = fmaxf(a, b);
    float sy = D0 * m * m;
    a = fmaxf((20.0f - xf) / 20.0f, 0.0f);
    b = fmaxf((xf - 363.0f) / 20.0f, 0.0f);
    m = fmaxf(a, b);
    float sx = D0 * m * m;
    return sy + sx;
}

__global__ __launch_bounds__(256) void init_coeff(
    const float* __restrict__ vp,
    float* __restrict__ v2p, float* __restrict__ bpad, float* __restrict__ invap)
{
    int i = blockIdx.x * 256 + threadIdx.x;
    if (i >= PNN) return;
    int py = i / PX, px = i - py * PX;
    int dy = py - PAD, dx = px - PAD;
    bool in = ((unsigned)dy < (unsigned)NY) && ((unsigned)dx < (unsigned)NX);
    float v = in ? vp[dy * NX + dx] : 0.0f;
    float sig = sigma_of(dy, dx);
    float a = 1.0f + HALF_DT * sig;
    v2p[i]   = v * v * DT2;
    bpad[i]  = 1.0f - HALF_DT * sig;
    invap[i] = in ? (1.0f / a) : 0.0f;   // Dirichlet mask folded in
}

__device__ __forceinline__ float4 ld4g(const float* p) { return *(const float4*)p; }
__device__ __forceinline__ void st4g(float* p, float4 v) { *(float4*)p = v; }
__device__ __forceinline__ float get4(const float4& v, int c) {
    return c == 0 ? v.x : c == 1 ? v.y : c == 2 ? v.z : v.w;
}
__device__ __forceinline__ void set4(float4& v, int c, float x) {
    if (c == 0) v.x = x; else if (c == 1) v.y = x; else if (c == 2) v.z = x; else v.w = x;
}

// 4-cell quad update. x-chain: [xm2a, xm1a, cen.x..w, xp1a, xp2a]
__device__ __forceinline__ float4 quad_update(
    float4 cen, float4 up, float4 v2, float4 bb, float4 ia,
    float4 ym2, float4 ym1, float4 yp1, float4 yp2,
    float xm2a, float xm1a, float xp1a, float xp2a)
{
    float4 r;
    float lyv, lxv, lap;
    lyv = C0 * (ym2.x + yp2.x) + C1 * (ym1.x + yp1.x) + C2 * cen.x;
    lxv = C0 * (xm2a + cen.z) + C1 * (xm1a + cen.y) + C2 * cen.x;
    lap = (lyv + lxv) * INV_DX2;
    r.x = (2.0f * cen.x - bb.x * up.x + v2.x * lap) * ia.x;
    lyv = C0 * (ym2.y + yp2.y) + C1 * (ym1.y + yp1.y) + C2 * cen.y;
    lxv = C0 * (xm1a + cen.w) + C1 * (cen.x + cen.z) + C2 * cen.y;
    lap = (lyv + lxv) * INV_DX2;
    r.y = (2.0f * cen.y - bb.y * up.y + v2.y * lap) * ia.y;
    lyv = C0 * (ym2.z + yp2.z) + C1 * (ym1.z + yp1.z) + C2 * cen.z;
    lxv = C0 * (cen.x + xp1a) + C1 * (cen.y + cen.w) + C2 * cen.z;
    lap = (lyv + lxv) * INV_DX2;
    r.z = (2.0f * cen.z - bb.z * up.z + v2.z * lap) * ia.z;
    lyv = C0 * (ym2.w + yp2.w) + C1 * (ym1.w + yp1.w) + C2 * cen.w;
    lxv = C0 * (cen.y + xp2a) + C1 * (cen.z + xp1a) + C2 * cen.w;
    lap = (lyv + lxv) * INV_DX2;
    r.w = (2.0f * cen.w - bb.w * up.w + v2.w * lap) * ia.w;
    return r;
}

__global__ __launch_bounds__(TPB) void stepK(
    float* __restrict__ ubuf,            // [S][4][PNN]
    const float* __restrict__ v2p, const float* __restrict__ bpad,
    const float* __restrict__ invap,
    const float* __restrict__ src_amp,   // [S, NT]
    const int* __restrict__ src_loc,     // [S, 2]
    const int* __restrict__ rec_loc,     // [S*NREC, 2]
    float* __restrict__ out,             // [S*NREC, NT]
    int t0, int pin, int pout)
{
    __shared__ __align__(16) float A0[SP * L];
    __shared__ __align__(16) float A1[SP * L];
    __shared__ int r_lidx[NREC];
    __shared__ int r_tout[NREC];
    __shared__ int r_cnt;

    const int tid = threadIdx.x;
    const int bx = blockIdx.x, by = blockIdx.y, s = blockIdx.z;
    const bool act = (tid < NPAIR);

    const float* upIn = ubuf + (size_t)(s * 4 + pin) * PNN;
    const float* ucIn = upIn + PNN;
    float* upOut = ubuf + (size_t)(s * 4 + pout) * PNN;
    float* ucOut = upOut + PNN;

    const int py0 = by * T;            // padded row of local (0,0)
    const int px0 = bx * T;
    const int gy0 = py0 - PAD;         // domain coords of local (0,0)
    const int gx0 = px0 - PAD;

    if (tid == 0) r_cnt = 0;

    // source geometry
    const int sy = src_loc[2 * s], sx = src_loc[2 * s + 1];
    const int sly = sy - gy0, slx = sx - gx0;
    const bool has_src = ((unsigned)sly < (unsigned)L) && ((unsigned)slx < (unsigned)L);
    const float4 a0 = ld4g(&src_amp[s * NT + t0]);
    const float4 a1 = ld4g(&src_amp[s * NT + t0 + 4]);

    // ---- per-thread setup: one vertical pair of quads (rows rl, rl+1) ----
    int rl = 0, qc4 = 0;
    float4 cenL = {}, cenU = {}, upL = {}, upU = {}, v2L = {}, v2U = {},
           bbL = {}, bbU = {}, iaL = {}, iaU = {}, saL = {}, saU = {};
    if (act) {
        int pr = tid / 20;
        qc4 = (tid - pr * 20) * 4;
        rl = 2 * pr;
        int pa = (py0 + rl) * PX + px0 + qc4;
        upL = ld4g(upIn + pa);        upU = ld4g(upIn + pa + PX);
        cenL = ld4g(ucIn + pa);       cenU = ld4g(ucIn + pa + PX);
        *(float4*)&A0[rl * SP + qc4] = cenL;
        *(float4*)&A0[(rl + 1) * SP + qc4] = cenU;
        v2L = ld4g(v2p + pa);         v2U = ld4g(v2p + pa + PX);
        bbL = ld4g(bpad + pa);        bbU = ld4g(bpad + pa + PX);
        iaL = ld4g(invap + pa);       iaU = ld4g(invap + pa + PX);
        if (has_src && slx >= qc4 && slx < qc4 + 4) {
            int c = slx - qc4;
            if (sly == rl)          set4(saL, c, get4(v2L, c));
            else if (sly == rl + 1) set4(saU, c, get4(v2U, c));
        }
    }
    __syncthreads();   // covers r_cnt init + A0 writes

    // receiver ownership scan (unique interior owner)
    if (tid < NREC) {
        int r = s * NREC + tid;
        int ry = rec_loc[2 * r], rx = rec_loc[2 * r + 1];
        if (ry >= by * T && ry < by * T + T && rx >= bx * T && rx < bx * T + T) {
            int k = atomicAdd(&r_cnt, 1);
            r_lidx[k] = (ry - gy0) * SP + (rx - gx0);
            r_tout[k] = r * NT + t0;
        }
    }

#pragma unroll
    for (int j = 0; j < K; ++j) {
        const int m = 2 * (j + 1);
        const float* Ain = (j & 1) ? A1 : A0;
        float* Aout = (j & 1) ? A0 : A1;
        const float aj = (j == 0) ? a0.x : (j == 1) ? a0.y : (j == 2) ? a0.z :
                         (j == 3) ? a0.w : (j == 4) ? a1.x : (j == 5) ? a1.y :
                         (j == 6) ? a1.z : a1.w;

        if (act && rl >= m && rl < L - m && qc4 + 3 >= m && qc4 < L - m) {
            const int b = rl * SP + qc4;
            float4 rm2 = *(const float4*)&Ain[b - 2 * SP];
            float4 rm1 = *(const float4*)&Ain[b - SP];
            float4 rp2 = *(const float4*)&Ain[b + 2 * SP];
            float4 rp3 = *(const float4*)&Ain[b + 3 * SP];
            float2 xmL = *(const float2*)&Ain[b - 2];
            float2 xpL = *(const float2*)&Ain[b + 4];
            float2 xmU = *(const float2*)&Ain[b + SP - 2];
            float2 xpU = *(const float2*)&Ain[b + SP + 4];
            float4 rL = quad_update(cenL, upL, v2L, bbL, iaL, rm2, rm1, cenU, rp2,
                                    xmL.x, xmL.y, xpL.x, xpL.y);
            float4 rU = quad_update(cenU, upU, v2U, bbU, iaU, rm1, cenL, rp2, rp3,
                                    xmU.x, xmU.y, xpU.x, xpU.y);
            rL.x += aj * saL.x; rL.y += aj * saL.y; rL.z += aj * saL.z; rL.w += aj * saL.w;
            rU.x += aj * saU.x; rU.y += aj * saU.y; rU.z += aj * saU.z; rU.w += aj * saU.w;
            *(float4*)&Aout[b] = rL;
            *(float4*)&Aout[b + SP] = rU;
            upL = cenL; cenL = rL;
            upU = cenU; cenU = rU;
        }
        __syncthreads();
        if (tid < r_cnt) out[r_tout[tid] + j] = Aout[r_lidx[tid]];
    }

    // ---- store interior of final pair: cen = u(t0+K), up = u(t0+K-1) ----
    if (act && rl >= PAD && rl < L - PAD && qc4 >= PAD && qc4 < L - PAD) {
        int pa = (py0 + rl) * PX + px0 + qc4;
        st4g(ucOut + pa, cenL);       st4g(upOut + pa, upL);
        st4g(ucOut + pa + PX, cenU);  st4g(upOut + pa + PX, upU);
    }
}

extern "C" void kernel_launch(void* const* d_in, const int* in_sizes, int n_in,
                              void* d_out, int out_size, void* d_ws, size_t ws_size,
                              hipStream_t stream)
{
    const float* vp      = (const float*)d_in[0];
    const float* src_amp = (const float*)d_in[1];
    const int*   src_loc = (const int*)d_in[2];
    const int*   rec_loc = (const int*)d_in[3];
    float* out = (float*)d_out;

    // ws layout: v2p | bpad | invap | ubuf[S][4][PNN]
    float* ws = (float*)d_ws;
    float* v2p   = ws;
    float* bpad  = v2p + PNN;
    float* invap = bpad + PNN;
    float* ubuf  = invap + PNN;

    hipMemsetAsync(ubuf, 0, (size_t)S * 4 * PNN * sizeof(float), stream);
    init_coeff<<<(PNN + 255) / 256, 256, 0, stream>>>(vp, v2p, bpad, invap);

    for (int l = 0; l < NT / K; ++l) {
        int pin = (l & 1) ? 2 : 0;
        int pout = (l & 1) ? 0 : 2;
        stepK<<<dim3(TB, TB, S), TPB, 0, stream>>>(
            ubuf, v2p, bpad, invap, src_amp, src_loc, rec_loc, out,
            l * K, pin, pout);
    }
}